// Round 8
// baseline (214.689 us; speedup 1.0000x reference)
//
#include <hip/hip_runtime.h>
#include <hip/hip_bf16.h>

#define NATC 10000
#define NNC 32
#define RSNC 16
#define THETANC 8
#define NEMBC 4
#define FEATC 576

typedef __attribute__((ext_vector_type(8))) short short8;  // 8 bf16 (4 VGPRs)
typedef __attribute__((ext_vector_type(4))) float f32x4;

union Frag { uint4 u; short8 s; };

static __device__ __forceinline__ short f2bf(float x) {
    union { __hip_bfloat16 h; short s; } u;
    u.h = __float2bfloat16(x);
    return u.s;
}

// pack two fp32 -> (bf16(hi)<<16)|bf16(lo) with round-half-up bias: 3 VALU ops
static __device__ __forceinline__ unsigned int pk2(float lo, float hi) {
    const unsigned int ul = __float_as_uint(lo) + 0x8000u;
    const unsigned int uh = __float_as_uint(hi) + 0x8000u;
    return __builtin_amdgcn_perm(uh, ul, 0x07060302u);
}

static __device__ __forceinline__ float fast_tanh(float x) {
    const float xc = fminf(fmaxf(x, -9.0f), 9.0f);
    const float e = __expf(2.0f * xc);
    return __fdividef(e - 1.0f, e + 1.0f);
}

// ---------------------------------------------------------------------------
// Kernel 0: pack W1 (576x64) and W2 (64x64) into bf16 MFMA B-fragment order.
// B-frag (16x16x32): lane l supplies W[k = ks*32 + (l>>4)*8 + jj][n = nt*16 + (l&15)]
// stored Wp[((ks*4+nt)*64 + l)*8 + jj].  W1: 18 ks; W2: 2 ks.
// ---------------------------------------------------------------------------
__global__ __launch_bounds__(256) void prep_kernel(
    const float* __restrict__ W1, const float* __restrict__ W2,
    ushort* __restrict__ W1p, ushort* __restrict__ W2p)
{
    const int gid = blockIdx.x * 256 + threadIdx.x;   // 0..5119
    const float* W = (gid < 4608) ? W1 : W2;
    ushort* Wp = (gid < 4608) ? W1p : W2p;
    const int g = (gid < 4608) ? gid : gid - 4608;
    const int l = g & 63, ntks = g >> 6;
    const int nt = ntks & 3, ks = ntks >> 2;
    const int q = l >> 4, c = l & 15;
    ushort pk[8];
    #pragma unroll
    for (int jj = 0; jj < 8; ++jj)
        pk[jj] = (ushort)f2bf(W[(ks * 32 + q * 8 + jj) * 64 + nt * 16 + c]);
    #pragma unroll
    for (int jj = 0; jj < 8; ++jj) Wp[g * 8 + jj] = pk[jj];
}

// ---------------------------------------------------------------------------
// Kernel 1: FUSED descriptor + MLP. One block (256 thr = 4 waves) per atom.
//  - native __sinf/__cosf/__expf transcendentals (bf16-bound outputs)
//  - v_perm bf16 pair-pack for Pb and A-fragments
//  - layer1/layer2 via m=1 MFMA with PRE-PACKED W1p/W2p (round-7's on-the-fly
//    build was the 144us regression; round-6's fence was the 240us one)
//  - zero-padded drowz/h1bz: A-row-0 masking costs 1 cndmask per ks, not 4
//  - one fire-and-forget atomicAdd per block
// ---------------------------------------------------------------------------
__global__ __launch_bounds__(256, 4) void desc_kernel(
    const float* __restrict__ pos,
    const float* __restrict__ spe,
    const float* __restrict__ theta_s,
    const float* __restrict__ kn_rad,
    const int* __restrict__ nidx,
    const ushort* __restrict__ W1p,
    const float* __restrict__ b1,
    const ushort* __restrict__ W2p,
    const float* __restrict__ b2,
    const float* __restrict__ W3,
    const float* __restrict__ b3,
    float* __restrict__ out)
{
    constexpr float RC = 5.0f;
    constexpr float PI_F = 3.14159265358979323846f;
    constexpr float PREF = 3.0517578125e-05f; // 2^(1-16)

    __shared__ __attribute__((aligned(16))) float ux[NNC], uy[NNC], uz[NNC];
    __shared__ __attribute__((aligned(16))) float rbase[NNC], rw[NNC];
    __shared__ __attribute__((aligned(16))) float bfs[NNC * 17];
    __shared__ __attribute__((aligned(16))) float ses[NNC * 5];
    __shared__ __attribute__((aligned(16))) float P[NNC * 66];      // fp32, pad 66
    __shared__ __attribute__((aligned(16))) float cosm[NNC * 36];   // 144B rows
    __shared__ __attribute__((aligned(16))) float sinm[NNC * 36];
    __shared__ __attribute__((aligned(16))) short Pb[4 * 64 * 8];   // bf16 B-frags
    __shared__ __attribute__((aligned(16))) ushort drowz[8 + FEATC]; // [0..7]=0 pad
    __shared__ __attribute__((aligned(16))) ushort h1bz[8 + 64];     // [0..7]=0 pad
    __shared__ __attribute__((aligned(16))) float h1p[64];
    __shared__ float red[4];

    const int i   = blockIdx.x;
    const int tid = threadIdx.x;

    // --- phase 0: bond geometry (32 threads) + zero pads ---
    if (tid < 8) { drowz[tid] = 0; h1bz[tid] = 0; }
    if (tid < NNC) {
        const int j = tid;
        const int n = nidx[i * NNC + j];
        const float pix = pos[i * 3 + 0], piy = pos[i * 3 + 1], piz = pos[i * 3 + 2];
        const float dx = pos[n * 3 + 0] - pix;
        const float dy = pos[n * 3 + 1] - piy;
        const float dz = pos[n * 3 + 2] - piz;
        const float r = sqrtf(dx * dx + dy * dy + dz * dz) + 1e-8f;
        const float inv = __fdividef(1.0f, r);
        ux[j] = dx * inv; uy[j] = dy * inv; uz[j] = dz * inv;
        const float fc = (r < RC) ? 0.5f * (__cosf(PI_F * r * (1.0f / RC)) + 1.0f) : 0.0f;
        rbase[j] = sqrtf(2.0f / RC) * inv * fc;
        rw[j]    = (PI_F / RC) * kn_rad[0] * r;
        #pragma unroll
        for (int m = 0; m < NEMBC; ++m)
            ses[j * 5 + m] = spe[n * NEMBC + m] * spe[i * NEMBC + m];
    }
    __syncthreads();

    // --- phase 1: bessel basis (512 items), native sin ---
    #pragma unroll
    for (int k = 0; k < 2; ++k) {
        const int e = tid + k * 256;
        const int j = e >> 4, l = e & 15;
        bfs[j * 17 + l] = rbase[j] * __sinf(rw[j] * (float)(l + 1));
    }
    __syncthreads();

    // --- phase 2: P fp32 (stride 66) + cos/sin matrix (stride 36) ---
    #pragma unroll
    for (int k = 0; k < 8; ++k) {
        const int e = tid + k * 256;
        const int j = e >> 6, p = e & 63;
        P[j * 66 + p] = bfs[j * 17 + (p >> 2)] * ses[j * 5 + (p & 3)];
    }
    #pragma unroll
    for (int k = 0; k < 4; ++k) {
        const int idx = tid + k * 256;
        const int j = idx >> 5, kk = idx & 31;
        float c = ux[j] * ux[kk] + uy[j] * uy[kk] + uz[j] * uz[kk];
        c = fminf(fmaxf(c, -1.0f + 1e-6f), 1.0f - 1e-6f);
        cosm[j * 36 + kk] = c;
        sinm[j * 36 + kk] = __builtin_amdgcn_sqrtf(fmaxf(1.0f - c * c, 0.0f));
    }
    __syncthreads();

    // --- phase 3: pack Pb (bf16 B-frags via v_perm) + radial descriptor ---
    {
        const int nt = tid >> 6, l2 = tid & 63;
        const int q2 = l2 >> 4, c2 = l2 & 15;
        float v[8];
        #pragma unroll
        for (int jj = 0; jj < 8; ++jj)
            v[jj] = P[(q2 * 8 + jj) * 66 + nt * 16 + c2];
        Frag f;
        f.u = make_uint4(pk2(v[0], v[1]), pk2(v[2], v[3]),
                         pk2(v[4], v[5]), pk2(v[6], v[7]));
        *(uint4*)&Pb[(nt * 64 + l2) * 8] = f.u;
    }
    if (tid < 64) {
        float s = 0.0f;
        #pragma unroll 8
        for (int j = 0; j < NNC; ++j) s += P[j * 66 + tid];
        drowz[8 + tid] = (ushort)f2bf(s);
    }
    __syncthreads();

    // --- phase 4: MFMA angular contraction per theta ---
    const int w = tid >> 6, l = tid & 63;
    const int q = l >> 4, c = l & 15;

    for (int tt = 0; tt < 2; ++tt) {
        const int t = w + tt * 4;
        const float th = theta_s[t];
        const float ct = __cosf(th), st = __sinf(th);

        short8 afr[2];
        #pragma unroll
        for (int mt = 0; mt < 2; ++mt) {
            const int kk = mt * 16 + c;
            const float4 c0 = *(const float4*)&cosm[kk * 36 + q * 8];
            const float4 c1 = *(const float4*)&cosm[kk * 36 + q * 8 + 4];
            const float4 s0 = *(const float4*)&sinm[kk * 36 + q * 8];
            const float4 s1 = *(const float4*)&sinm[kk * 36 + q * 8 + 4];
            float cv[8], sv[8];
            cv[0]=c0.x; cv[1]=c0.y; cv[2]=c0.z; cv[3]=c0.w;
            cv[4]=c1.x; cv[5]=c1.y; cv[6]=c1.z; cv[7]=c1.w;
            sv[0]=s0.x; sv[1]=s0.y; sv[2]=s0.z; sv[3]=s0.w;
            sv[4]=s1.x; sv[5]=s1.y; sv[6]=s1.z; sv[7]=s1.w;
            float a[8];
            #pragma unroll
            for (int jj = 0; jj < 8; ++jj) {
                const float cosd = fmaf(cv[jj], ct, sv[jj] * st);
                const float x = 1.0f + cosd;
                const float x2 = x * x, x4 = x2 * x2, x8 = x4 * x4;
                a[jj] = PREF * (x8 * x8);
            }
            Frag f;
            f.u = make_uint4(pk2(a[0], a[1]), pk2(a[2], a[3]),
                             pk2(a[4], a[5]), pk2(a[6], a[7]));
            afr[mt] = f.s;
        }

        f32x4 acc[2][4];
        #pragma unroll
        for (int mt = 0; mt < 2; ++mt)
            #pragma unroll
            for (int nt = 0; nt < 4; ++nt)
                acc[mt][nt] = (f32x4){0.0f, 0.0f, 0.0f, 0.0f};

        #pragma unroll
        for (int nt = 0; nt < 4; ++nt) {
            const short8 bfr = *(const short8*)&Pb[(nt * 64 + l) * 8];
            acc[0][nt] = __builtin_amdgcn_mfma_f32_16x16x32_bf16(afr[0], bfr, acc[0][nt], 0, 0, 0);
            acc[1][nt] = __builtin_amdgcn_mfma_f32_16x16x32_bf16(afr[1], bfr, acc[1][nt], 0, 0, 0);
        }

        float pt[4];
        #pragma unroll
        for (int nt = 0; nt < 4; ++nt) {
            float s = 0.0f;
            #pragma unroll
            for (int mt = 0; mt < 2; ++mt)
                #pragma unroll
                for (int r = 0; r < 4; ++r) {
                    const int kk = mt * 16 + q * 4 + r;
                    s = fmaf(acc[mt][nt][r], P[kk * 66 + nt * 16 + c], s);
                }
            s += __shfl_xor(s, 16, 64);
            s += __shfl_xor(s, 32, 64);
            pt[nt] = s;
        }
        const float v = (q == 0) ? pt[0] : (q == 1) ? pt[1] : (q == 2) ? pt[2] : pt[3];
        drowz[8 + 64 + t * 64 + l] = (ushort)f2bf(v);
    }
    __syncthreads();

    // --- phase 5: layer1 via m=1 MFMA with packed W1p ---
    {
        f32x4 acc1 = (f32x4){0.0f, 0.0f, 0.0f, 0.0f};
        #pragma unroll 3
        for (int ks = 0; ks < 18; ++ks) {
            const short8 bfr = *(const short8*)&W1p[((ks * 4 + w) * 64 + l) * 8];
            const int aoff = (c == 0) ? (8 + ks * 32 + q * 8) : 0;  // pad rows = 0
            const short8 afr = *(const short8*)&drowz[aoff];
            acc1 = __builtin_amdgcn_mfma_f32_16x16x32_bf16(afr, bfr, acc1, 0, 0, 0);
        }
        if (l < 16) h1p[w * 16 + l] = acc1[0];   // D row 0
    }
    __syncthreads();

    // --- phase 6: tanh -> bf16 h1, layer2 via m=1 MFMA with packed W2p ---
    if (tid < 64) h1bz[8 + tid] = (ushort)f2bf(fast_tanh(h1p[tid] + b1[tid]));
    __syncthreads();
    {
        f32x4 acc2 = (f32x4){0.0f, 0.0f, 0.0f, 0.0f};
        #pragma unroll
        for (int ks = 0; ks < 2; ++ks) {
            const short8 bfr = *(const short8*)&W2p[((ks * 4 + w) * 64 + l) * 8];
            const int aoff = (c == 0) ? (8 + ks * 32 + q * 8) : 0;
            const short8 afr = *(const short8*)&h1bz[aoff];
            acc2 = __builtin_amdgcn_mfma_f32_16x16x32_bf16(afr, bfr, acc2, 0, 0, 0);
        }
        float s = 0.0f;
        if (l < 16) s = fast_tanh(acc2[0] + b2[w * 16 + l]) * W3[w * 16 + l];
        s += __shfl_xor(s, 1, 64);
        s += __shfl_xor(s, 2, 64);
        s += __shfl_xor(s, 4, 64);
        s += __shfl_xor(s, 8, 64);
        if (l == 0) red[w] = s;
    }
    __syncthreads();

    // --- phase 7: one fire-and-forget atomic per block ---
    if (tid == 0)
        atomicAdd(out, (red[0] + red[1]) + (red[2] + red[3]) + b3[0]);
}

extern "C" void kernel_launch(void* const* d_in, const int* in_sizes, int n_in,
                              void* d_out, int out_size, void* d_ws, size_t ws_size,
                              hipStream_t stream)
{
    const float* pos   = (const float*)d_in[0];
    const float* spe   = (const float*)d_in[1];
    const float* theta = (const float*)d_in[2];
    const float* kn    = (const float*)d_in[3];
    const float* W1    = (const float*)d_in[4];
    const float* b1    = (const float*)d_in[5];
    const float* W2    = (const float*)d_in[6];
    const float* b2    = (const float*)d_in[7];
    const float* W3    = (const float*)d_in[8];
    const float* b3    = (const float*)d_in[9];
    const int*   nidx  = (const int*)d_in[10];
    float* out = (float*)d_out;

    // workspace: W1p [4608*8 u16] | W2p [512*8 u16]
    ushort* W1p = (ushort*)d_ws;
    ushort* W2p = W1p + 4608 * 8;

    hipMemsetAsync(out, 0, sizeof(float), stream);
    prep_kernel<<<20, 256, 0, stream>>>(W1, W2, W1p, W2p);
    desc_kernel<<<NATC, 256, 0, stream>>>(pos, spe, theta, kn, nidx,
                                          W1p, b1, W2p, b2, W3, b3, out);
}

// Round 9
// 157.045 us; speedup vs baseline: 1.3671x; 1.3671x over previous
//
#include <hip/hip_runtime.h>
#include <hip/hip_bf16.h>

#define NATC 10000
#define NATP 10016          // padded atom count for MFMA m-tiles
#define NNC 32
#define RSNC 16
#define THETANC 8
#define NEMBC 4
#define FEATC 576

typedef __attribute__((ext_vector_type(8))) short short8;  // 8 bf16 (4 VGPRs)
typedef __attribute__((ext_vector_type(4))) float f32x4;

union Frag { uint4 u; short8 s; };

static __device__ __forceinline__ short f2bf(float x) {
    union { __hip_bfloat16 h; short s; } u;
    u.h = __float2bfloat16(x);
    return u.s;
}

// pack two fp32 -> (bf16(hi)<<16)|bf16(lo) with round-half-up bias: 3 VALU ops
static __device__ __forceinline__ unsigned int pk2(float lo, float hi) {
    const unsigned int ul = __float_as_uint(lo) + 0x8000u;
    const unsigned int uh = __float_as_uint(hi) + 0x8000u;
    return __builtin_amdgcn_perm(uh, ul, 0x07060302u);
}

static __device__ __forceinline__ float fast_tanh(float x) {
    const float xc = fminf(fmaxf(x, -9.0f), 9.0f);
    const float e = __expf(2.0f * xc);
    return __fdividef(e - 1.0f, e + 1.0f);
}

// ---------------------------------------------------------------------------
// Kernel 0: pack W1 (576x64) and W2 (64x64) into bf16 MFMA B-fragment order.
// ---------------------------------------------------------------------------
__global__ __launch_bounds__(256) void prep_kernel(
    const float* __restrict__ W1, const float* __restrict__ W2,
    ushort* __restrict__ W1p, ushort* __restrict__ W2p)
{
    const int gid = blockIdx.x * 256 + threadIdx.x;   // 0..5119
    if (gid < 4608) {                                 // W1: 18 ks * 4 nt * 64 l
        const int l = gid & 63, ntks = gid >> 6;
        const int nt = ntks & 3, ks = ntks >> 2;
        const int q = l >> 4, c = l & 15;
        ushort pk[8];
        #pragma unroll
        for (int jj = 0; jj < 8; ++jj)
            pk[jj] = (ushort)f2bf(W1[(ks * 32 + q * 8 + jj) * 64 + nt * 16 + c]);
        #pragma unroll
        for (int jj = 0; jj < 8; ++jj) W1p[gid * 8 + jj] = pk[jj];
    } else {                                          // W2: 2 ks * 4 nt * 64 l
        const int g = gid - 4608;
        const int l = g & 63, ntks = g >> 6;
        const int nt = ntks & 3, ks = ntks >> 2;
        const int q = l >> 4, c = l & 15;
        ushort pk[8];
        #pragma unroll
        for (int jj = 0; jj < 8; ++jj)
            pk[jj] = (ushort)f2bf(W2[(ks * 32 + q * 8 + jj) * 64 + nt * 16 + c]);
        #pragma unroll
        for (int jj = 0; jj < 8; ++jj) W2p[g * 8 + jj] = pk[jj];
    }
}

// ---------------------------------------------------------------------------
// Kernel 1: per-atom descriptor via MFMA — EXACT round-4 structure (80us,
// VALU 62%, occ 58%: the best measured) with only the fast-math numerics
// validated in round 8 (absmax stayed 0.0): __sinf/__cosf, native sqrt,
// v_perm pair-pack. No layout/LDS/sync changes.
// ---------------------------------------------------------------------------
__global__ __launch_bounds__(256, 4) void desc_kernel(
    const float* __restrict__ pos,
    const float* __restrict__ spe,
    const float* __restrict__ theta_s,
    const float* __restrict__ kn_rad,
    const int* __restrict__ nidx,
    ushort* __restrict__ descb)
{
    constexpr float RC = 5.0f;
    constexpr float PI_F = 3.14159265358979323846f;
    constexpr float PREF = 3.0517578125e-05f; // 2^(1-16)

    __shared__ __attribute__((aligned(16))) float ux[NNC], uy[NNC], uz[NNC];
    __shared__ __attribute__((aligned(16))) float rbase[NNC], rw[NNC];
    __shared__ __attribute__((aligned(16))) float bfs[NNC * 17];
    __shared__ __attribute__((aligned(16))) float ses[NNC * 5];
    __shared__ __attribute__((aligned(16))) float P[NNC * 65];      // fp32, pad 65
    __shared__ __attribute__((aligned(16))) float cosm[NNC * 33];   // pad 33
    __shared__ __attribute__((aligned(16))) float sinm[NNC * 33];
    __shared__ __attribute__((aligned(16))) short Pb[4 * 64 * 8];   // bf16 B-frags

    const int i   = blockIdx.x;
    const int tid = threadIdx.x;

    // --- phase 0: bond geometry (32 threads) ---
    if (tid < NNC) {
        const int j = tid;
        const int n = nidx[i * NNC + j];
        const float pix = pos[i * 3 + 0], piy = pos[i * 3 + 1], piz = pos[i * 3 + 2];
        const float dx = pos[n * 3 + 0] - pix;
        const float dy = pos[n * 3 + 1] - piy;
        const float dz = pos[n * 3 + 2] - piz;
        const float r = sqrtf(dx * dx + dy * dy + dz * dz) + 1e-8f;
        const float inv = __fdividef(1.0f, r);
        ux[j] = dx * inv; uy[j] = dy * inv; uz[j] = dz * inv;
        const float fc = (r < RC) ? 0.5f * (__cosf(PI_F * r * (1.0f / RC)) + 1.0f) : 0.0f;
        rbase[j] = sqrtf(2.0f / RC) * inv * fc;
        rw[j]    = (PI_F / RC) * kn_rad[0] * r;
        #pragma unroll
        for (int m = 0; m < NEMBC; ++m)
            ses[j * 5 + m] = spe[n * NEMBC + m] * spe[i * NEMBC + m];
    }
    __syncthreads();

    // --- phase 1: bessel basis (512 items), native sin ---
    #pragma unroll
    for (int k = 0; k < 2; ++k) {
        const int e = tid + k * 256;
        const int j = e >> 4, l = e & 15;
        bfs[j * 17 + l] = rbase[j] * __sinf(rw[j] * (float)(l + 1));
    }
    __syncthreads();

    // --- phase 2: P fp32 (stride 65) + cos/sin matrix (stride 33) ---
    #pragma unroll
    for (int k = 0; k < 8; ++k) {
        const int e = tid + k * 256;
        const int j = e >> 6, p = e & 63;
        P[j * 65 + p] = bfs[j * 17 + (p >> 2)] * ses[j * 5 + (p & 3)];
    }
    #pragma unroll
    for (int k = 0; k < 4; ++k) {
        const int idx = tid + k * 256;
        const int j = idx >> 5, kk = idx & 31;
        float c = ux[j] * ux[kk] + uy[j] * uy[kk] + uz[j] * uz[kk];
        c = fminf(fmaxf(c, -1.0f + 1e-6f), 1.0f - 1e-6f);
        cosm[j * 33 + kk] = c;
        sinm[j * 33 + kk] = __builtin_amdgcn_sqrtf(fmaxf(1.0f - c * c, 0.0f));
    }
    __syncthreads();

    // --- phase 3: pack Pb (bf16 B-frags via v_perm) + radial descriptor ---
    {
        const int nt = tid >> 6, l2 = tid & 63;
        const int q2 = l2 >> 4, c2 = l2 & 15;
        float v[8];
        #pragma unroll
        for (int jj = 0; jj < 8; ++jj)
            v[jj] = P[(q2 * 8 + jj) * 65 + nt * 16 + c2];
        Frag f;
        f.u = make_uint4(pk2(v[0], v[1]), pk2(v[2], v[3]),
                         pk2(v[4], v[5]), pk2(v[6], v[7]));
        *(uint4*)&Pb[(nt * 64 + l2) * 8] = f.u;
    }
    if (tid < 64) {
        float s = 0.0f;
        #pragma unroll 8
        for (int j = 0; j < NNC; ++j) s += P[j * 65 + tid];
        descb[(size_t)i * FEATC + tid] = (ushort)f2bf(s);
    }
    __syncthreads();

    // --- phase 4: MFMA contraction per theta (scalar stride-33 A reads) ---
    const int w = tid >> 6, l = tid & 63;
    const int q = l >> 4, c = l & 15;

    for (int tt = 0; tt < 2; ++tt) {
        const int t = w + tt * 4;
        const float th = theta_s[t];
        const float ct = __cosf(th), st = __sinf(th);

        short8 afr[2];
        #pragma unroll
        for (int mt = 0; mt < 2; ++mt) {
            const int kk = mt * 16 + c;
            float a[8];
            #pragma unroll
            for (int jj = 0; jj < 8; ++jj) {
                const int j = q * 8 + jj;
                const float cv = cosm[kk * 33 + j];
                const float sv = sinm[kk * 33 + j];
                const float cosd = fmaf(cv, ct, sv * st);
                const float x = 1.0f + cosd;
                const float x2 = x * x, x4 = x2 * x2, x8 = x4 * x4;
                a[jj] = PREF * (x8 * x8);
            }
            Frag f;
            f.u = make_uint4(pk2(a[0], a[1]), pk2(a[2], a[3]),
                             pk2(a[4], a[5]), pk2(a[6], a[7]));
            afr[mt] = f.s;
        }

        f32x4 acc[2][4];
        #pragma unroll
        for (int mt = 0; mt < 2; ++mt)
            #pragma unroll
            for (int nt = 0; nt < 4; ++nt)
                acc[mt][nt] = (f32x4){0.0f, 0.0f, 0.0f, 0.0f};

        #pragma unroll
        for (int nt = 0; nt < 4; ++nt) {
            const short8 bfr = *(const short8*)&Pb[(nt * 64 + l) * 8];
            acc[0][nt] = __builtin_amdgcn_mfma_f32_16x16x32_bf16(afr[0], bfr, acc[0][nt], 0, 0, 0);
            acc[1][nt] = __builtin_amdgcn_mfma_f32_16x16x32_bf16(afr[1], bfr, acc[1][nt], 0, 0, 0);
        }

        // epilogue: ang[p] = sum_k B[k][p] * P[k][p]
        float pt[4];
        #pragma unroll
        for (int nt = 0; nt < 4; ++nt) {
            float s = 0.0f;
            #pragma unroll
            for (int mt = 0; mt < 2; ++mt)
                #pragma unroll
                for (int r = 0; r < 4; ++r) {
                    const int kk = mt * 16 + q * 4 + r;
                    s = fmaf(acc[mt][nt][r], P[kk * 65 + nt * 16 + c], s);
                }
            s += __shfl_xor(s, 16, 64);
            s += __shfl_xor(s, 32, 64);
            pt[nt] = s;
        }
        const float v = (q == 0) ? pt[0] : (q == 1) ? pt[1] : (q == 2) ? pt[2] : pt[3];
        descb[(size_t)i * FEATC + 64 + t * 64 + l] = (ushort)f2bf(v);
    }
}

// ---------------------------------------------------------------------------
// Kernel 2: MFMA MLP — round-4 structure, fast_tanh only change.
// ---------------------------------------------------------------------------
__global__ __launch_bounds__(256) void mlp_kernel(
    const ushort* __restrict__ descb,
    const ushort* __restrict__ W1p, const float* __restrict__ b1,
    const ushort* __restrict__ W2p, const float* __restrict__ b2,
    const float* __restrict__ W3, const float* __restrict__ b3,
    float* __restrict__ out)
{
    __shared__ __attribute__((aligned(16))) ushort H1b[32 * 72];
    __shared__ float red[4];

    const int tid = threadIdx.x;
    const int w = tid >> 6, l = tid & 63;
    const int q = l >> 4, c = l & 15;
    const int a0 = blockIdx.x * 32;

    f32x4 acc[2];
    acc[0] = (f32x4){0.0f, 0.0f, 0.0f, 0.0f};
    acc[1] = (f32x4){0.0f, 0.0f, 0.0f, 0.0f};

    #pragma unroll 3
    for (int ks = 0; ks < 18; ++ks) {
        const short8 b = *(const short8*)&W1p[((ks * 4 + w) * 64 + l) * 8];
        #pragma unroll
        for (int mt = 0; mt < 2; ++mt) {
            const int a = a0 + mt * 16 + c;   // < NATP (padded), poison rows masked later
            const short8 afr = *(const short8*)&descb[(size_t)a * FEATC + ks * 32 + q * 8];
            acc[mt] = __builtin_amdgcn_mfma_f32_16x16x32_bf16(afr, b, acc[mt], 0, 0, 0);
        }
    }

    const float b1v = b1[w * 16 + c];
    #pragma unroll
    for (int mt = 0; mt < 2; ++mt)
        #pragma unroll
        for (int r = 0; r < 4; ++r) {
            const int m = mt * 16 + q * 4 + r;          // atom-local row
            H1b[m * 72 + w * 16 + c] = (ushort)f2bf(fast_tanh(acc[mt][r] + b1v));
        }
    __syncthreads();

    f32x4 acc2[2];
    acc2[0] = (f32x4){0.0f, 0.0f, 0.0f, 0.0f};
    acc2[1] = (f32x4){0.0f, 0.0f, 0.0f, 0.0f};
    #pragma unroll
    for (int ks = 0; ks < 2; ++ks) {
        const short8 b = *(const short8*)&W2p[((ks * 4 + w) * 64 + l) * 8];
        #pragma unroll
        for (int mt = 0; mt < 2; ++mt) {
            const short8 afr = *(const short8*)&H1b[(mt * 16 + c) * 72 + ks * 32 + q * 8];
            acc2[mt] = __builtin_amdgcn_mfma_f32_16x16x32_bf16(afr, b, acc2[mt], 0, 0, 0);
        }
    }

    const float b2v = b2[w * 16 + c];
    const float w3v = W3[w * 16 + c];
    float s = 0.0f;
    #pragma unroll
    for (int mt = 0; mt < 2; ++mt)
        #pragma unroll
        for (int r = 0; r < 4; ++r) {
            const int a = a0 + mt * 16 + q * 4 + r;
            const float e = fast_tanh(acc2[mt][r] + b2v) * w3v;
            if (a < NATC) s += e;
        }
    #pragma unroll
    for (int off = 1; off <= 32; off <<= 1)
        s += __shfl_xor(s, off, 64);
    if (l == 0) red[w] = s;
    __syncthreads();
    if (tid == 0) {
        float tot = red[0] + red[1] + red[2] + red[3];
        if (blockIdx.x == 0) tot += (float)NATC * b3[0];
        atomicAdd(out, tot);
    }
}

extern "C" void kernel_launch(void* const* d_in, const int* in_sizes, int n_in,
                              void* d_out, int out_size, void* d_ws, size_t ws_size,
                              hipStream_t stream)
{
    const float* pos   = (const float*)d_in[0];
    const float* spe   = (const float*)d_in[1];
    const float* theta = (const float*)d_in[2];
    const float* kn    = (const float*)d_in[3];
    const float* W1    = (const float*)d_in[4];
    const float* b1    = (const float*)d_in[5];
    const float* W2    = (const float*)d_in[6];
    const float* b2    = (const float*)d_in[7];
    const float* W3    = (const float*)d_in[8];
    const float* b3    = (const float*)d_in[9];
    const int*   nidx  = (const int*)d_in[10];
    float* out = (float*)d_out;

    // workspace layout (bytes): descb [NATP*576 u16] | W1p [36864 u16] | W2p [4096 u16]
    ushort* descb = (ushort*)d_ws;
    ushort* W1p   = (ushort*)((char*)d_ws + (size_t)NATP * FEATC * 2);
    ushort* W2p   = W1p + 4608 * 8;

    hipMemsetAsync(out, 0, sizeof(float), stream);
    prep_kernel<<<20, 256, 0, stream>>>(W1, W2, W1p, W2p);
    desc_kernel<<<NATC, 256, 0, stream>>>(pos, spe, theta, kn, nidx, descb);
    mlp_kernel<<<(NATC + 31) / 32, 256, 0, stream>>>(descb, W1p, b1, W2p, b2, W3, b3, out);
}